// Round 2
// baseline (88.119 us; speedup 1.0000x reference)
//
#include <hip/hip_runtime.h>

#define B_SZ  16
#define C_IN  32
#define C_OUT 32
#define HH    128
#define WW    128

// Block: 256 threads. Tile: 8 output channels x 16 output rows x 128 cols.
// Thread: 4 o x 4 rows x 4 cols register tile (64 fp32 accumulators).
// Grid: (8 row-tiles, 4 o-groups, 16 batch).
__global__ __launch_bounds__(256, 2) void geps_conv_kernel(
    const float* __restrict__ x, const float* __restrict__ codes,
    const float* __restrict__ weight, const float* __restrict__ A,
    const float* __restrict__ Bm, const float* __restrict__ bias,
    const float* __restrict__ bctx, float* __restrict__ out)
{
    __shared__ float lds_w[C_IN * 9 * 8];   // [i][kl][o8]
    __shared__ float lds_b[8];
    __shared__ float lds_x[4][18][WW];      // 4 in-ch x (16+2) rows x 128 cols

    const int tid = threadIdx.x;
    const int ht  = blockIdx.x;   // 0..7  (16-row tile)
    const int og  = blockIdx.y;   // 0..3  (8 out-ch group)
    const int b   = blockIdx.z;   // 0..15
    const int h0  = ht * 16;

    const float c00 = codes[b * 4 + 0];
    const float c01 = codes[b * 4 + 1];
    const float c10 = codes[b * 4 + 2];
    const float c11 = codes[b * 4 + 3];

    // Synthesize combined weights for this block's 8 output channels.
    // w[b,o,i,kl] = weight[o,i,kl] + sum_r (sum_c A[i,c,kl]*codes[b,c,r]) * Bm[o,r,kl]
    for (int j = tid; j < C_IN * 9 * 8; j += 256) {
        int i = j / 72, rem = j - i * 72, kl = rem >> 3, ol = rem & 7;
        int o = og * 8 + ol;
        float a0 = A[(i * 2 + 0) * 9 + kl];
        float a1 = A[(i * 2 + 1) * 9 + kl];
        float m0 = Bm[(o * 2 + 0) * 9 + kl];
        float m1 = Bm[(o * 2 + 1) * 9 + kl];
        float t0 = a0 * c00 + a1 * c10;
        float t1 = a0 * c01 + a1 * c11;
        lds_w[(i * 9 + kl) * 8 + ol] =
            weight[(o * C_IN + i) * 9 + kl] + (t0 * m0 + t1 * m1);
    }
    if (tid < 8) {
        int o = og * 8 + tid;
        lds_b[tid] = bias[o] + c00 * bctx[o] + c11 * bctx[32 + o];
    }

    const int w0 = (tid & 31) * 4;          // output col base
    const int r0 = ((tid >> 5) & 3) * 4;    // output row base (within 16-row tile)
    const int ob = (tid >> 7) * 4;          // local o base: 0 or 4

    float acc[4][4][4];
    #pragma unroll
    for (int o = 0; o < 4; ++o)
        #pragma unroll
        for (int r = 0; r < 4; ++r)
            #pragma unroll
            for (int c = 0; c < 4; ++c) acc[o][r][c] = 0.f;

    for (int cg = 0; cg < 8; ++cg) {        // 8 groups of 4 input channels
        __syncthreads();
        // Stage 4 ch x 18 rows x 128 cols (float4 loads), row-wrap at stage time.
        for (int j = tid; j < 4 * 18 * 32; j += 256) {
            int ci  = j / (18 * 32);
            int rem = j - ci * (18 * 32);
            int rr  = rem >> 5, wc = rem & 31;
            int grow = (h0 - 1 + rr) & 127;
            const float4 v = *(const float4*)(
                x + (((size_t)(b * C_IN + cg * 4 + ci) * HH + grow) * WW + wc * 4));
            *(float4*)&lds_x[ci][rr][wc * 4] = v;
        }
        __syncthreads();

        for (int ci = 0; ci < 4; ++ci) {
            const int i = cg * 4 + ci;
            // Load the 6-row x 6-col input window for this thread.
            float xs[6][6];
            #pragma unroll
            for (int rr = 0; rr < 6; ++rr) {
                const float* xrow = &lds_x[ci][r0 + rr][0];
                const float4 xm = *(const float4*)&xrow[w0];
                xs[rr][1] = xm.x; xs[rr][2] = xm.y; xs[rr][3] = xm.z; xs[rr][4] = xm.w;
                xs[rr][0] = xrow[(w0 + 127) & 127];   // col w0-1 (wrap)
                xs[rr][5] = xrow[(w0 + 4) & 127];     // col w0+4 (wrap)
            }
            #pragma unroll
            for (int k = 0; k < 3; ++k) {
                float wv[3][4];
                #pragma unroll
                for (int l = 0; l < 3; ++l)
                    *(float4*)&wv[l][0] = *(const float4*)&lds_w[(i * 9 + k * 3 + l) * 8 + ob];
                #pragma unroll
                for (int r = 0; r < 4; ++r)
                    #pragma unroll
                    for (int l = 0; l < 3; ++l)
                        #pragma unroll
                        for (int o = 0; o < 4; ++o)
                            #pragma unroll
                            for (int c = 0; c < 4; ++c)
                                acc[o][r][c] = fmaf(xs[r + k][c + l], wv[l][o], acc[o][r][c]);
            }
        }
    }

    // Epilogue: add per-sample bias, 16B stores.
    #pragma unroll
    for (int o = 0; o < 4; ++o) {
        const float bv = lds_b[ob + o];
        const int oo = og * 8 + ob + o;
        #pragma unroll
        for (int r = 0; r < 4; ++r) {
            float4 pk;
            pk.x = acc[o][r][0] + bv;
            pk.y = acc[o][r][1] + bv;
            pk.z = acc[o][r][2] + bv;
            pk.w = acc[o][r][3] + bv;
            *(float4*)&out[(((size_t)b * C_OUT + oo) * HH + (h0 + r0 + r)) * WW + w0] = pk;
        }
    }
}

extern "C" void kernel_launch(void* const* d_in, const int* in_sizes, int n_in,
                              void* d_out, int out_size, void* d_ws, size_t ws_size,
                              hipStream_t stream) {
    const float* x      = (const float*)d_in[0];
    const float* codes  = (const float*)d_in[1];
    const float* weight = (const float*)d_in[2];
    const float* A      = (const float*)d_in[3];
    const float* Bm     = (const float*)d_in[4];
    const float* bias   = (const float*)d_in[5];
    const float* bctx   = (const float*)d_in[6];
    float* out = (float*)d_out;

    dim3 grid(8, 4, 16), block(256);
    hipLaunchKernelGGL(geps_conv_kernel, grid, block, 0, stream,
                       x, codes, weight, A, Bm, bias, bctx, out);
}

// Round 3
// 26.268 us; speedup vs baseline: 3.3547x; 3.3547x over previous
//
#include <hip/hip_runtime.h>

typedef short bf16x8 __attribute__((ext_vector_type(8)));
typedef float f32x4  __attribute__((ext_vector_type(4)));
typedef unsigned short u16;
typedef unsigned int   u32;

#define HH 128
#define WW 128

__device__ __forceinline__ u16 f2bf(float f) {
    union { float f; u32 i; } v; v.f = f;
    u32 x = v.i;
    x += 0x7fffu + ((x >> 16) & 1u);   // round-to-nearest-even
    return (u16)(x >> 16);
}

// Implicit-GEMM conv via 9 shifted 32x32 channel GEMMs on mfma_f32_16x16x32_bf16.
// Block: 256 thr (4 waves), tile = 1 batch x 4 rows x 128 cols x 32 out-ch.
// Wave w owns output row h0+w (all 128 cols, all 32 o).
// Grid: 512 blocks (16 b x 32 row-blocks), XCD-bijective swizzled.
__global__ __launch_bounds__(256, 2) void geps_mfma_kernel(
    const float* __restrict__ x, const float* __restrict__ codes,
    const float* __restrict__ weight, const float* __restrict__ A,
    const float* __restrict__ Bm, const float* __restrict__ bias,
    const float* __restrict__ bctx, float* __restrict__ out)
{
    // [6 rows][8 slots][4 ig][16 p] x 8ch bf16 = 49152 B (B-frag = 1 linear b128)
    __shared__ bf16x8 lds_x[3072];
    // [9 kl][2 oh][4 kb][16 o] x 8i bf16 = 18432 B (A-frag = 1 linear b128)
    __shared__ bf16x8 lds_w[1152];
    __shared__ float  lds_ctx[576];   // [i][r][kl] = sum_c A[i,c,kl]*codes[c,r]
    __shared__ float  lds_b[32];

    const int tid = threadIdx.x;
    const int l   = tid & 63;
    const int wv  = tid >> 6;          // wave id 0..3 -> output row

    // XCD-aware bijective swizzle: 512 blocks = 8 XCDs x 64 contiguous.
    const int orig = blockIdx.x;
    const int vb   = (orig & 7) * 64 + (orig >> 3);
    const int rb   = vb & 31;          // row-block 0..31
    const int b    = vb >> 5;          // batch 0..15
    const int h0   = rb * 4;

    const float c00 = codes[b * 4 + 0];
    const float c01 = codes[b * 4 + 1];
    const float c10 = codes[b * 4 + 2];
    const float c11 = codes[b * 4 + 3];

    // ---- Phase 1: code contraction + per-sample bias ----
    for (int j = tid; j < 576; j += 256) {
        int i = j / 18, rem = j % 18, r = rem / 9, kl = rem % 9;
        float a0 = A[(i * 2 + 0) * 9 + kl];
        float a1 = A[(i * 2 + 1) * 9 + kl];
        lds_ctx[j] = (r == 0) ? (a0 * c00 + a1 * c10) : (a0 * c01 + a1 * c11);
    }
    if (tid < 32) lds_b[tid] = bias[tid] + c00 * bctx[tid] + c11 * bctx[32 + tid];
    __syncthreads();

    // ---- Phase 2a: synthesize combined weights -> bf16 LDS ----
    // item = (kl, o, kb); writes 8 contiguous i as one b128.
    for (int j = tid; j < 1152; j += 256) {
        int kl = j >> 7, rem = j & 127, o = rem >> 2, kb = rem & 3;
        float m0 = Bm[(o * 2 + 0) * 9 + kl];
        float m1 = Bm[(o * 2 + 1) * 9 + kl];
        bf16x8 w8;
        #pragma unroll
        for (int jj = 0; jj < 8; ++jj) {
            int i = kb * 8 + jj;
            float wf = weight[(o * 32 + i) * 9 + kl]
                     + lds_ctx[(i * 2 + 0) * 9 + kl] * m0
                     + lds_ctx[(i * 2 + 1) * 9 + kl] * m1;
            w8[jj] = (short)f2bf(wf);
        }
        lds_w[kl * 128 + (o >> 4) * 64 + kb * 16 + (o & 15)] = w8;
    }

    // ---- Phase 2b: stage x channel-last bf16 (6 rows, wrap at stage) ----
    // item = (row, ig, col-pair): 8 x float2 global, 2 x b128 LDS write.
    for (int it = 0; it < 6; ++it) {
        int idx = it * 256 + tid;      // < 1536
        int cp  = idx & 63;
        int ig  = (idx >> 6) & 3;
        int row = idx >> 8;            // 0..5
        int c0  = cp * 2;
        int grow = (h0 - 1 + row) & 127;
        const float* src = x + ((size_t)(b * 32 + ig * 8) * HH + grow) * WW + c0;
        bf16x8 v0, v1;
        #pragma unroll
        for (int jj = 0; jj < 8; ++jj) {
            float2 f = *(const float2*)(src + (size_t)jj * HH * WW);
            v0[jj] = (short)f2bf(f.x);
            v1[jj] = (short)f2bf(f.y);
        }
        int didx = row * 512 + (c0 >> 4) * 64 + ig * 16 + (c0 & 15);
        lds_x[didx]     = v0;
        lds_x[didx + 1] = v1;
    }
    __syncthreads();

    // ---- A fragments: all 18 resident (72 VGPRs) ----
    const int awb = (l >> 4) * 16 + (l & 15);
    bf16x8 af[9][2];
    #pragma unroll
    for (int kl = 0; kl < 9; ++kl)
        #pragma unroll
        for (int oh = 0; oh < 2; ++oh)
            af[kl][oh] = lds_w[kl * 128 + oh * 64 + awb];

    // ---- B-address bases per tap-column shift dl in {-1,0,1} ----
    const int p = l & 15, ig = l >> 4;
    int bb[3];
    #pragma unroll
    for (int dl = -1; dl <= 1; ++dl) {
        int pq = p + dl;                       // -1..16
        bb[dl + 1] = (pq & 15) + ((pq >> 4) << 6) + ig * 16;  // 16B-elem units
    }

    f32x4 acc[2][8];
    #pragma unroll
    for (int oh = 0; oh < 2; ++oh)
        #pragma unroll
        for (int nt = 0; nt < 8; ++nt)
            acc[oh][nt] = (f32x4){0.f, 0.f, 0.f, 0.f};

    #pragma unroll
    for (int nt = 0; nt < 8; ++nt) {
        #pragma unroll
        for (int lc = 0; lc < 3; ++lc) {
            int t = (bb[lc] + nt * 64) & 511;  // col wrap within row (512 elems)
            #pragma unroll
            for (int k = 0; k < 3; ++k) {
                bf16x8 bf = lds_x[(wv + k) * 512 + t];
                acc[0][nt] = __builtin_amdgcn_mfma_f32_16x16x32_bf16(
                    af[k * 3 + lc][0], bf, acc[0][nt], 0, 0, 0);
                acc[1][nt] = __builtin_amdgcn_mfma_f32_16x16x32_bf16(
                    af[k * 3 + lc][1], bf, acc[1][nt], 0, 0, 0);
            }
        }
    }

    // ---- Epilogue: bias + store (D: col=lane&15, row=(lane>>4)*4+reg) ----
    float bl[2][4];
    #pragma unroll
    for (int oh = 0; oh < 2; ++oh)
        #pragma unroll
        for (int r = 0; r < 4; ++r)
            bl[oh][r] = lds_b[oh * 16 + (l >> 4) * 4 + r];

    const int h = h0 + wv;
    const size_t obase = ((size_t)(b * 32 + (l >> 4) * 4) * HH + h) * WW + p;
    #pragma unroll
    for (int oh = 0; oh < 2; ++oh)
        #pragma unroll
        for (int nt = 0; nt < 8; ++nt)
            #pragma unroll
            for (int r = 0; r < 4; ++r)
                out[obase + (size_t)(oh * 16 + r) * (HH * WW) + nt * 16] =
                    acc[oh][nt][r] + bl[oh][r];
}

extern "C" void kernel_launch(void* const* d_in, const int* in_sizes, int n_in,
                              void* d_out, int out_size, void* d_ws, size_t ws_size,
                              hipStream_t stream) {
    const float* x      = (const float*)d_in[0];
    const float* codes  = (const float*)d_in[1];
    const float* weight = (const float*)d_in[2];
    const float* A      = (const float*)d_in[3];
    const float* Bm     = (const float*)d_in[4];
    const float* bias   = (const float*)d_in[5];
    const float* bctx   = (const float*)d_in[6];
    float* out = (float*)d_out;

    hipLaunchKernelGGL(geps_mfma_kernel, dim3(512), dim3(256), 0, stream,
                       x, codes, weight, A, Bm, bias, bctx, out);
}